// Round 17
// baseline (23.844 us; speedup 1.0000x reference)
//
#include <hip/hip_runtime.h>
#include <math.h>

typedef __attribute__((ext_vector_type(8))) short short8;
typedef __attribute__((ext_vector_type(4))) float f32x4;
typedef __attribute__((ext_vector_type(4))) unsigned int uint4v;

#define NPX 8192
#define NPATCH 8192
#define SPLITS 16
#define TILES 32             // 16-patch tiles per split (512 patches/split)
#define WPB 8                // waves per block (512 threads)
#define PXB 16               // pixel-blocks: 16 * 8 waves * 64 px = 8192

__device__ __forceinline__ float fexp2(float x) {
#if __has_builtin(__builtin_amdgcn_exp2f)
    return __builtin_amdgcn_exp2f(x);
#else
    return exp2f(x);
#endif
}

__device__ __forceinline__ unsigned short f2bf(float f) {
    unsigned u = __float_as_uint(f);
    u = u + 0x7FFFu + ((u >> 16) & 1u);
    return (unsigned short)(u >> 16);
}
__device__ __forceinline__ float bf2f(unsigned short h) {
    return __uint_as_float(((unsigned)h) << 16);
}
// pack truncated bf16(e1):bf16(e0) in one op
__device__ __forceinline__ unsigned pack_hi16(unsigned u1, unsigned u0) {
#if __has_builtin(__builtin_amdgcn_perm)
    return __builtin_amdgcn_perm(u1, u0, 0x07060302u);
#else
    return (u1 & 0xFFFF0000u) | (u0 >> 16);
#endif
}

// ---- prep: A-fragments (patches hi only, slot27=B2, slot28=1.0),
//            B-fragments (pixels hi only, slot27=1.0, slot28=-mhat),
//            V-fragments (centers+ones: hi in k-elems 0..3, lo in 4..7).
__global__ void __launch_bounds__(256) prep(const float* __restrict__ x,
                          const float* __restrict__ patches,
                          const float* __restrict__ t,
                          float* __restrict__ gAh,
                          float* __restrict__ gBh,
                          float* __restrict__ gVh) {
    int id = blockIdx.x * 256 + threadIdx.x;
    float bt2 = t[0];
    float at = sqrtf(1.0f - bt2);
    const float L2E = 1.4426950408889634f;
    if (id < NPATCH) {
        int p = id;
        const float* src = patches + p * 27;
        float v[27]; float pn = 0.f;
#pragma unroll
        for (int k = 0; k < 27; k++) { v[k] = src[k]; pn += v[k] * v[k]; }
        float A2 = at * L2E / bt2;
        float B2 = -at * at * pn * L2E / (2.0f * bt2);
        float sv[28];
#pragma unroll
        for (int k = 0; k < 27; k++) sv[k] = A2 * v[k];
        sv[27] = B2;
        int j = p >> 4, pi = p & 15;
        short8* Ah8 = (short8*)gAh;
#pragma unroll
        for (int c = 0; c < 4; c++) {
            short8 H;
#pragma unroll
            for (int i = 0; i < 8; i++) {
                int k = c * 8 + i;
                unsigned short hb = 0;
                if (k < 28) hb = f2bf(sv[k]);
                else if (k == 28) hb = 0x3F80;   // 1.0: multiplies -mhat
                H[i] = (short)hb;
            }
            Ah8[j * 64 + c * 16 + pi] = H;
        }
    } else if (id < NPATCH + NPX) {
        int px = id - NPATCH;
        int b = px >> 10, rem = px & 1023, h = rem >> 5, w = rem & 31;
        float xv[28];
        float xn = 0.f;
#pragma unroll
        for (int c3 = 0; c3 < 3; c3++)
#pragma unroll
        for (int dr = 0; dr < 3; dr++)
#pragma unroll
        for (int dc = 0; dc < 3; dc++) {
            int hh = h + dr - 1, ww = w + dc - 1;
            float val = 0.f;
            if ((unsigned)hh < 32u && (unsigned)ww < 32u)
                val = x[b * 3072 + c3 * 1024 + hh * 32 + ww];
            xv[c3 * 9 + dr * 3 + dc] = val;
            xn += val * val;
        }
        xv[27] = 1.0f;
        // analytic logit upper bound (log2 units), window-shifted by -40
        float mraw = L2E * xn / (2.0f * bt2) - 40.0f;
        unsigned short mh = f2bf(mraw);            // mhat = bf2f(mh)
        int wv = px >> 4, pi = px & 15;
        short8* Bh8 = (short8*)gBh;
#pragma unroll
        for (int c = 0; c < 4; c++) {
            short8 H;
#pragma unroll
            for (int i = 0; i < 8; i++) {
                int k = c * 8 + i;
                unsigned short hb = 0;
                if (k < 28) hb = f2bf(xv[k]);
                else if (k == 28) hb = (unsigned short)(mh ^ 0x8000u);   // -mhat
                H[i] = (short)hb;
            }
            Bh8[wv * 64 + c * 16 + pi] = H;
        }
    } else {
        // V-fragments: elems 0..3 = center hi (patches 4g..4g+3), elems 4..7 = lo.
        // cols 0..2 = channel centers, col 3 = ones (S column). Other cols zero.
        int vid = id - (NPATCH + NPX);          // 0 .. 512*64-1
        int tile = vid >> 6, lane = vid & 63;
        int g = (lane >> 4) & 3, col = lane & 15;
        short8 H;
#pragma unroll
        for (int i = 0; i < 8; i++) {
            unsigned short bb = 0;
            if (col < 4) {
                int ii = i & 3;
                float val;
                if (col == 3) val = 1.0f;       // ones column -> S
                else {
                    int p = tile * 16 + 4 * g + ii;
                    val = patches[p * 27 + (col == 0 ? 4 : col == 1 ? 13 : 22)];
                }
                unsigned short hb = f2bf(val);
                bb = (i < 4) ? hb : f2bf(val - bf2f(hb));   // hi then lo
            }
            H[i] = (short)bb;
        }
        ((short8*)gVh)[vid] = H;
    }
}

// ---- main: QK logits (-mhat pre-folded), exp2, PV via MFMA ----
__global__ void __launch_bounds__(512) main_mfma(
        const float* __restrict__ gAh,
        const float* __restrict__ gBh,
        const float* __restrict__ gVh,
        float* __restrict__ ps,
        float* __restrict__ pc0, float* __restrict__ pc1, float* __restrict__ pc2) {
    __shared__ short8 sAh[TILES * 64];   // 32 KB each, 64 KB total -> 2 blocks/CU
    __shared__ short8 sVh[TILES * 64];
    const int tid = threadIdx.x;
    const int lane = tid & 63, wid = tid >> 6;
    const int split = blockIdx.x, pxb = blockIdx.y;
    const int tb = split * TILES;

    // stage A-hi, V fragment records (coalesced float4; 8 per thread)
    {
        const float4* s0 = (const float4*)gAh + tb * 64;
        const float4* s2 = (const float4*)gVh + tb * 64;
        float4* d0 = (float4*)sAh; float4* d2 = (float4*)sVh;
#pragma unroll
        for (int i = 0; i < 4; i++) {
            d0[tid + i * 512] = s0[tid + i * 512];
            d2[tid + i * 512] = s2[tid + i * 512];
        }
    }

    // pixel fragments: 4 groups of 16 pixels per wave (64 px/wave)
    const int pxg = pxb * WPB + wid;             // 0..127
    short8 bh[4];
#pragma unroll
    for (int j = 0; j < 4; j++)
        bh[j] = ((const short8*)gBh)[(pxg * 4 + j) * 64 + lane];
    __syncthreads();

    const f32x4 z4 = {0.f, 0.f, 0.f, 0.f};
    f32x4 O[4] = {z4, z4, z4, z4};
#pragma unroll 4
    for (int tt = 0; tt < TILES; tt++) {
        short8 ah = sAh[tt * 64 + lane];
        short8 vh = sVh[tt * 64 + lane];
#pragma unroll
        for (int j = 0; j < 4; j++) {
            f32x4 d = __builtin_amdgcn_mfma_f32_16x16x32_bf16(ah, bh[j], z4, 0, 0, 0);
            // d <= ~40 by the analytic bound -> e <= 2^41, no clamp needed
            unsigned u0 = __float_as_uint(fexp2(d.x));
            unsigned u1 = __float_as_uint(fexp2(d.y));
            unsigned u2 = __float_as_uint(fexp2(d.z));
            unsigned u3 = __float_as_uint(fexp2(d.w));
            uint4v pu;
            pu.x = pack_hi16(u1, u0);
            pu.y = pack_hi16(u3, u2);
            pu.z = pu.x; pu.w = pu.y;     // duplicate P for the V-lo K-slots
            short8 pa = __builtin_bit_cast(short8, pu);
            O[j] = __builtin_amdgcn_mfma_f32_16x16x32_bf16(pa, vh, O[j], 0, 0, 0);
        }
    }

    // ---- write partials: lane holds channel ch=lane&15, pixels 4*(lane>>4)+reg ----
    const int ch = lane & 15, rg = lane >> 4;
    if (ch < 4) {
        float* dst = (ch == 0) ? pc0 : (ch == 1) ? pc1 : (ch == 2) ? pc2 : ps;
#pragma unroll
        for (int j = 0; j < 4; j++) {
            int base = split * NPX + (pxg * 4 + j) * 16 + 4 * rg;
            dst[base + 0] = O[j].x;
            dst[base + 1] = O[j].y;
            dst[base + 2] = O[j].z;
            dst[base + 3] = O[j].w;
        }
    }
}

// ---- combine: pure sum over splits (shared mhat cancels in C/S) ----
__global__ void __launch_bounds__(64) combine(const float* __restrict__ x, const float* __restrict__ t,
                        const float* __restrict__ ps,
                        const float* __restrict__ pc0, const float* __restrict__ pc1,
                        const float* __restrict__ pc2, float* __restrict__ out) {
    int px = blockIdx.x * 64 + threadIdx.x;
    if (px >= NPX) return;
    float S = 0.0f, C0 = 0.0f, C1 = 0.0f, C2 = 0.0f;
#pragma unroll 8
    for (int sp = 0; sp < SPLITS; sp++) {
        int o = sp * NPX + px;
        S  += ps[o];
        C0 += pc0[o];
        C1 += pc1[o];
        C2 += pc2[o];
    }
    float bt2 = t[0];
    float at = sqrtf(1.0f - bt2);
    float invS = 1.0f / fmaxf(S, 1e-37f);
    float ibt = 1.0f / bt2;
    int b = px >> 10, rem = px & 1023, h = rem >> 5, w = rem & 31;
    int xi = b * 3072 + h * 32 + w;
    out[xi]        = (at * C0 * invS - x[xi]) * ibt;
    out[xi + 1024] = (at * C1 * invS - x[xi + 1024]) * ibt;
    out[xi + 2048] = (at * C2 * invS - x[xi + 2048]) * ibt;
}

extern "C" void kernel_launch(void* const* d_in, const int* in_sizes, int n_in,
                              void* d_out, int out_size, void* d_ws, size_t ws_size,
                              hipStream_t stream) {
    const float* x = (const float*)d_in[0];
    const float* patches = (const float*)d_in[1];
    const float* t = (const float*)d_in[2];
    float* out = (float*)d_out;
    float* ws = (float*)d_ws;

    float* gAh = ws;                      // 131072 floats each
    float* gBh = ws + 131072;
    float* gVh = ws + 262144;
    float* ps  = ws + 393216;             // 16*8192 floats each -> total ~3.5 MB
    float* pc0 = ps + SPLITS * NPX;
    float* pc1 = pc0 + SPLITS * NPX;
    float* pc2 = pc1 + SPLITS * NPX;

    hipLaunchKernelGGL(prep, dim3(192), dim3(256), 0, stream,
                       x, patches, t, gAh, gBh, gVh);
    hipLaunchKernelGGL(main_mfma, dim3(SPLITS, PXB), dim3(WPB * 64), 0, stream,
                       gAh, gBh, gVh, ps, pc0, pc1, pc2);
    hipLaunchKernelGGL(combine, dim3(NPX / 64), dim3(64), 0, stream,
                       x, t, ps, pc0, pc1, pc2, out);
}

// Round 18
// 22.900 us; speedup vs baseline: 1.0412x; 1.0412x over previous
//
#include <hip/hip_runtime.h>
#include <math.h>

typedef __attribute__((ext_vector_type(8))) short short8;
typedef __attribute__((ext_vector_type(4))) float f32x4;
typedef __attribute__((ext_vector_type(4))) unsigned int uint4v;

#define NPX 8192
#define NPATCH 8192
#define SPLITS 16
#define TILES 32             // 16-patch tiles per split (512 patches/split)
#define WPB 8                // waves per block (512 threads)
#define PXB 32               // pixel-blocks: 32 * 8 waves * 32 px = 8192

__device__ __forceinline__ float fexp2(float x) {
#if __has_builtin(__builtin_amdgcn_exp2f)
    return __builtin_amdgcn_exp2f(x);
#else
    return exp2f(x);
#endif
}

__device__ __forceinline__ unsigned short f2bf(float f) {
    unsigned u = __float_as_uint(f);
    u = u + 0x7FFFu + ((u >> 16) & 1u);
    return (unsigned short)(u >> 16);
}
__device__ __forceinline__ float bf2f(unsigned short h) {
    return __uint_as_float(((unsigned)h) << 16);
}
// pack truncated bf16(e1):bf16(e0) in one op
__device__ __forceinline__ unsigned pack_hi16(unsigned u1, unsigned u0) {
#if __has_builtin(__builtin_amdgcn_perm)
    return __builtin_amdgcn_perm(u1, u0, 0x07060302u);
#else
    return (u1 & 0xFFFF0000u) | (u0 >> 16);
#endif
}

// ---- prep: A-fragments (patches hi only, slot27=B2, slot28=1.0),
//            B-fragments (pixels hi only, slot27=1.0, slot28=-mhat),
//            V-fragments (centers+ones: hi in k-elems 0..3, lo in 4..7).
__global__ void __launch_bounds__(256) prep(const float* __restrict__ x,
                          const float* __restrict__ patches,
                          const float* __restrict__ t,
                          float* __restrict__ gAh,
                          float* __restrict__ gBh,
                          float* __restrict__ gVh) {
    int id = blockIdx.x * 256 + threadIdx.x;
    float bt2 = t[0];
    float at = sqrtf(1.0f - bt2);
    const float L2E = 1.4426950408889634f;
    if (id < NPATCH) {
        int p = id;
        const float* src = patches + p * 27;
        float v[27]; float pn = 0.f;
#pragma unroll
        for (int k = 0; k < 27; k++) { v[k] = src[k]; pn += v[k] * v[k]; }
        float A2 = at * L2E / bt2;
        float B2 = -at * at * pn * L2E / (2.0f * bt2);
        float sv[28];
#pragma unroll
        for (int k = 0; k < 27; k++) sv[k] = A2 * v[k];
        sv[27] = B2;
        int j = p >> 4, pi = p & 15;
        short8* Ah8 = (short8*)gAh;
#pragma unroll
        for (int c = 0; c < 4; c++) {
            short8 H;
#pragma unroll
            for (int i = 0; i < 8; i++) {
                int k = c * 8 + i;
                unsigned short hb = 0;
                if (k < 28) hb = f2bf(sv[k]);
                else if (k == 28) hb = 0x3F80;   // 1.0: multiplies -mhat
                H[i] = (short)hb;
            }
            Ah8[j * 64 + c * 16 + pi] = H;
        }
    } else if (id < NPATCH + NPX) {
        int px = id - NPATCH;
        int b = px >> 10, rem = px & 1023, h = rem >> 5, w = rem & 31;
        float xv[28];
        float xn = 0.f;
#pragma unroll
        for (int c3 = 0; c3 < 3; c3++)
#pragma unroll
        for (int dr = 0; dr < 3; dr++)
#pragma unroll
        for (int dc = 0; dc < 3; dc++) {
            int hh = h + dr - 1, ww = w + dc - 1;
            float val = 0.f;
            if ((unsigned)hh < 32u && (unsigned)ww < 32u)
                val = x[b * 3072 + c3 * 1024 + hh * 32 + ww];
            xv[c3 * 9 + dr * 3 + dc] = val;
            xn += val * val;
        }
        xv[27] = 1.0f;
        // analytic logit upper bound (log2 units), window-shifted by -40
        float mraw = L2E * xn / (2.0f * bt2) - 40.0f;
        unsigned short mh = f2bf(mraw);            // mhat = bf2f(mh)
        int wv = px >> 4, pi = px & 15;
        short8* Bh8 = (short8*)gBh;
#pragma unroll
        for (int c = 0; c < 4; c++) {
            short8 H;
#pragma unroll
            for (int i = 0; i < 8; i++) {
                int k = c * 8 + i;
                unsigned short hb = 0;
                if (k < 28) hb = f2bf(xv[k]);
                else if (k == 28) hb = (unsigned short)(mh ^ 0x8000u);   // -mhat
                H[i] = (short)hb;
            }
            Bh8[wv * 64 + c * 16 + pi] = H;
        }
    } else {
        // V-fragments: elems 0..3 = center hi (patches 4g..4g+3), elems 4..7 = lo.
        // cols 0..2 = channel centers, col 3 = ones (S column). Other cols zero.
        int vid = id - (NPATCH + NPX);          // 0 .. 512*64-1
        int tile = vid >> 6, lane = vid & 63;
        int g = (lane >> 4) & 3, col = lane & 15;
        short8 H;
#pragma unroll
        for (int i = 0; i < 8; i++) {
            unsigned short bb = 0;
            if (col < 4) {
                int ii = i & 3;
                float val;
                if (col == 3) val = 1.0f;       // ones column -> S
                else {
                    int p = tile * 16 + 4 * g + ii;
                    val = patches[p * 27 + (col == 0 ? 4 : col == 1 ? 13 : 22)];
                }
                unsigned short hb = f2bf(val);
                bb = (i < 4) ? hb : f2bf(val - bf2f(hb));   // hi then lo
            }
            H[i] = (short)bb;
        }
        ((short8*)gVh)[vid] = H;
    }
}

// ---- main: QK logits (-mhat pre-folded), exp2, PV via MFMA ----
__global__ void __launch_bounds__(512) main_mfma(
        const float* __restrict__ gAh,
        const float* __restrict__ gBh,
        const float* __restrict__ gVh,
        float* __restrict__ ps,
        float* __restrict__ pc0, float* __restrict__ pc1, float* __restrict__ pc2) {
    __shared__ short8 sAh[TILES * 64];   // 32 KB each, 64 KB total -> 2 blocks/CU
    __shared__ short8 sVh[TILES * 64];
    const int tid = threadIdx.x;
    const int lane = tid & 63, wid = tid >> 6;
    const int split = blockIdx.x, pxb = blockIdx.y;
    const int tb = split * TILES;

    // stage A-hi, V fragment records (coalesced float4; 8 per thread)
    {
        const float4* s0 = (const float4*)gAh + tb * 64;
        const float4* s2 = (const float4*)gVh + tb * 64;
        float4* d0 = (float4*)sAh; float4* d2 = (float4*)sVh;
#pragma unroll
        for (int i = 0; i < 4; i++) {
            d0[tid + i * 512] = s0[tid + i * 512];
            d2[tid + i * 512] = s2[tid + i * 512];
        }
    }

    // pixel fragments: 2 groups of 16 pixels per wave (32 px/wave)
    const int pxg = pxb * WPB + wid;             // 0..255
    short8 bh[2];
    bh[0] = ((const short8*)gBh)[(pxg * 2 + 0) * 64 + lane];
    bh[1] = ((const short8*)gBh)[(pxg * 2 + 1) * 64 + lane];
    __syncthreads();

    const f32x4 z4 = {0.f, 0.f, 0.f, 0.f};
    f32x4 O[2] = {z4, z4};
#pragma unroll 4
    for (int tt = 0; tt < TILES; tt++) {
        short8 ah = sAh[tt * 64 + lane];
        short8 vh = sVh[tt * 64 + lane];
#pragma unroll
        for (int j = 0; j < 2; j++) {
            f32x4 d = __builtin_amdgcn_mfma_f32_16x16x32_bf16(ah, bh[j], z4, 0, 0, 0);
            // d <= ~40 by the analytic bound -> e <= 2^41, no clamp needed
            unsigned u0 = __float_as_uint(fexp2(d.x));
            unsigned u1 = __float_as_uint(fexp2(d.y));
            unsigned u2 = __float_as_uint(fexp2(d.z));
            unsigned u3 = __float_as_uint(fexp2(d.w));
            uint4v pu;
            pu.x = pack_hi16(u1, u0);
            pu.y = pack_hi16(u3, u2);
            pu.z = pu.x; pu.w = pu.y;     // duplicate P for the V-lo K-slots
            short8 pa = __builtin_bit_cast(short8, pu);
            O[j] = __builtin_amdgcn_mfma_f32_16x16x32_bf16(pa, vh, O[j], 0, 0, 0);
        }
    }

    // ---- write partials: lane holds channel ch=lane&15, pixels 4*(lane>>4)+reg ----
    const int ch = lane & 15, rg = lane >> 4;
    if (ch < 4) {
        float* dst = (ch == 0) ? pc0 : (ch == 1) ? pc1 : (ch == 2) ? pc2 : ps;
#pragma unroll
        for (int j = 0; j < 2; j++) {
            int base = split * NPX + (pxg * 2 + j) * 16 + 4 * rg;
            dst[base + 0] = O[j].x;
            dst[base + 1] = O[j].y;
            dst[base + 2] = O[j].z;
            dst[base + 3] = O[j].w;
        }
    }
}

// ---- combine: pure sum over splits (shared mhat cancels in C/S) ----
__global__ void __launch_bounds__(64) combine(const float* __restrict__ x, const float* __restrict__ t,
                        const float* __restrict__ ps,
                        const float* __restrict__ pc0, const float* __restrict__ pc1,
                        const float* __restrict__ pc2, float* __restrict__ out) {
    int px = blockIdx.x * 64 + threadIdx.x;
    if (px >= NPX) return;
    float S = 0.0f, C0 = 0.0f, C1 = 0.0f, C2 = 0.0f;
#pragma unroll 8
    for (int sp = 0; sp < SPLITS; sp++) {
        int o = sp * NPX + px;
        S  += ps[o];
        C0 += pc0[o];
        C1 += pc1[o];
        C2 += pc2[o];
    }
    float bt2 = t[0];
    float at = sqrtf(1.0f - bt2);
    float invS = 1.0f / fmaxf(S, 1e-37f);
    float ibt = 1.0f / bt2;
    int b = px >> 10, rem = px & 1023, h = rem >> 5, w = rem & 31;
    int xi = b * 3072 + h * 32 + w;
    out[xi]        = (at * C0 * invS - x[xi]) * ibt;
    out[xi + 1024] = (at * C1 * invS - x[xi + 1024]) * ibt;
    out[xi + 2048] = (at * C2 * invS - x[xi + 2048]) * ibt;
}

extern "C" void kernel_launch(void* const* d_in, const int* in_sizes, int n_in,
                              void* d_out, int out_size, void* d_ws, size_t ws_size,
                              hipStream_t stream) {
    const float* x = (const float*)d_in[0];
    const float* patches = (const float*)d_in[1];
    const float* t = (const float*)d_in[2];
    float* out = (float*)d_out;
    float* ws = (float*)d_ws;

    float* gAh = ws;                      // 131072 floats each
    float* gBh = ws + 131072;
    float* gVh = ws + 262144;
    float* ps  = ws + 393216;             // 16*8192 floats each -> total ~3.5 MB
    float* pc0 = ps + SPLITS * NPX;
    float* pc1 = pc0 + SPLITS * NPX;
    float* pc2 = pc1 + SPLITS * NPX;

    hipLaunchKernelGGL(prep, dim3(192), dim3(256), 0, stream,
                       x, patches, t, gAh, gBh, gVh);
    hipLaunchKernelGGL(main_mfma, dim3(SPLITS, PXB), dim3(WPB * 64), 0, stream,
                       gAh, gBh, gVh, ps, pc0, pc1, pc2);
    hipLaunchKernelGGL(combine, dim3(NPX / 64), dim3(64), 0, stream,
                       x, t, ps, pc0, pc1, pc2, out);
}